// Round 4
// baseline (7975.830 us; speedup 1.0000x reference)
//
#include <hip/hip_runtime.h>

#define B_   64
#define T_   512
#define NE   1024
#define ND   512

typedef float f4 __attribute__((ext_vector_type(4)));

// ---------------- ws layout (floats) ----------------
#define WS_TH0   0         // th buffer 0: [64][1024]
#define WS_TH1   65536     // th buffer 1
#define WS_LAST  131072    // last_enc [64][1024]
#define WS_BAR   196608    // 16 group counters, stride 32 uints (128B)
#define WS_ZERO_F4 49280

__global__ __launch_bounds__(256) void init_ws(float4* __restrict__ ws4) {
    int i = blockIdx.x * 256 + threadIdx.x;
    if (i < WS_ZERO_F4) ws4[i] = make_float4(0.f, 0.f, 0.f, 0.f);
}

// inline, call-free tanh: 1 - 2/(e^{2x}+1); exact at +-inf, ~1e-7 rel err
__device__ __forceinline__ float fast_tanh(float x) {
    float e = __expf(2.0f * x);
    return 1.0f - 2.0f / (e + 1.0f);
}

#define MACQ(A, Jv, T) \
    A = fmaf(Jv.x, T.x, A); A = fmaf(Jv.y, T.y, A); \
    A = fmaf(Jv.z, T.z, A); A = fmaf(Jv.w, T.w, A);

#define STEPJ(j) { \
    const f4 t0 = *(const f4*)&th_lds[       ks4 + (j)*128]; \
    const f4 t1 = *(const f4*)&th_lds[1024 + ks4 + (j)*128]; \
    const f4 t2 = *(const f4*)&th_lds[2048 + ks4 + (j)*128]; \
    const f4 t3 = *(const f4*)&th_lds[3072 + ks4 + (j)*128]; \
    MACQ(a00, J0_##j, t0) MACQ(a01, J1_##j, t0) MACQ(a02, J2_##j, t0) MACQ(a03, J3_##j, t0) \
    MACQ(a10, J0_##j, t1) MACQ(a11, J1_##j, t1) MACQ(a12, J2_##j, t1) MACQ(a13, J3_##j, t1) \
    MACQ(a20, J0_##j, t2) MACQ(a21, J1_##j, t2) MACQ(a22, J2_##j, t2) MACQ(a23, J3_##j, t2) \
    MACQ(a30, J0_##j, t3) MACQ(a31, J1_##j, t3) MACQ(a32, J2_##j, t3) MACQ(a33, J3_##j, t3) }

#define JLOAD(ni) \
    J##ni##_0 = *(const f4*)(Jp##ni +   0); J##ni##_1 = *(const f4*)(Jp##ni + 128); \
    J##ni##_2 = *(const f4*)(Jp##ni + 256); J##ni##_3 = *(const f4*)(Jp##ni + 384); \
    J##ni##_4 = *(const f4*)(Jp##ni + 512); J##ni##_5 = *(const f4*)(Jp##ni + 640); \
    J##ni##_6 = *(const f4*)(Jp##ni + 768); J##ni##_7 = *(const f4*)(Jp##ni + 896);

#define JPIN(ni) \
    asm volatile("" : "+v"(J##ni##_0)); asm volatile("" : "+v"(J##ni##_1)); \
    asm volatile("" : "+v"(J##ni##_2)); asm volatile("" : "+v"(J##ni##_3)); \
    asm volatile("" : "+v"(J##ni##_4)); asm volatile("" : "+v"(J##ni##_5)); \
    asm volatile("" : "+v"(J##ni##_6)); asm volatile("" : "+v"(J##ni##_7));

// Persistent encoder: 256 blocks (1/CU), 512 threads.
// Block (pb=bid>>4, ng=bid&15): batches [pb*4,+4), neurons [ng*64,+64).
// Thread (ks=tid>>4, ng4=tid&15): 4n x 4b x 32k tile; J pinned in 32 f4 regs.
// No calls in the loop (fast_tanh inline) so J stays register-resident.
__global__ __launch_bounds__(512, 2)
void enc_persist(const float* __restrict__ X, const float* __restrict__ noise,
                 const float* __restrict__ W_in, const float* __restrict__ J,
                 const float* __restrict__ in_s, const int* __restrict__ BT,
                 float* __restrict__ th0, float* __restrict__ th1,
                 float* __restrict__ last, unsigned* __restrict__ bar)
{
    __shared__ float th_lds[4096];    // 4 batches x 1024
    __shared__ float red[8704];       // [ks]*272 + [b]*68 + [n 0..63]

    const int tid = threadIdx.x;
    const int bid = blockIdx.x;
    const int pb  = bid >> 4;
    const int nb  = (bid & 15) * 64;
    const int ks  = tid >> 4;
    const int ng4 = tid & 15;
    const int ks4 = ks * 4;

    // ---- J fragment -> 32 named f4 (128 VGPRs), pinned ----
    const float* Jp0 = J + (size_t)(nb + ng4 * 4 + 0) * NE + ks4;
    const float* Jp1 = J + (size_t)(nb + ng4 * 4 + 1) * NE + ks4;
    const float* Jp2 = J + (size_t)(nb + ng4 * 4 + 2) * NE + ks4;
    const float* Jp3 = J + (size_t)(nb + ng4 * 4 + 3) * NE + ks4;
    f4 J0_0, J0_1, J0_2, J0_3, J0_4, J0_5, J0_6, J0_7;
    f4 J1_0, J1_1, J1_2, J1_3, J1_4, J1_5, J1_6, J1_7;
    f4 J2_0, J2_1, J2_2, J2_3, J2_4, J2_5, J2_6, J2_7;
    f4 J3_0, J3_1, J3_2, J3_3, J3_4, J3_5, J3_6, J3_7;
    JLOAD(0) JLOAD(1) JLOAD(2) JLOAD(3)
    JPIN(0) JPIN(1) JPIN(2) JPIN(3)

    // ---- owner state ----
    const int bo  = tid >> 6;
    const int nl  = tid & 63;
    const int bg  = pb * 4 + bo;
    const int ng_ = nb + nl;
    float hreg = 0.f, w0 = 0.f, w1 = 0.f;
    int bt = -999;
    const float is0 = in_s[0], is1 = in_s[1];
    if (tid < 256) {
        w0 = W_in[ng_ * 2 + 0];
        w1 = W_in[ng_ * 2 + 1];
        bt = BT[bg];
    }

    const int m = max(max(BT[pb * 4 + 0], BT[pb * 4 + 1]),
                      max(BT[pb * 4 + 2], BT[pb * 4 + 3]));
    unsigned* cnt = bar + pb * 32;

    for (int t = 0; t < m; ++t) {
        float* __restrict__ cur = (t & 1) ? th1 : th0;
        float* __restrict__ nxt = (t & 1) ? th0 : th1;

        // ---- prefetch drive terms (issued before the gate; immutable data) ----
        float nz = 0.f, xa = 0.f, xb = 0.f;
        if (tid < 256) {
            nz = noise[((size_t)bg * T_ + t) * NE + ng_];
            xa = X[((size_t)bg * T_ + t) * 2 + 0];
            xb = X[((size_t)bg * T_ + t) * 2 + 1];
        }

        // ---- gate: group's step-(t-1) publishes visible? ----
        if (t > 0) {
            if (tid == 0) {
                const unsigned tgt = 16u * (unsigned)t;
                while (__hip_atomic_load(cnt, __ATOMIC_RELAXED,
                                         __HIP_MEMORY_SCOPE_AGENT) < tgt)
                    __builtin_amdgcn_s_sleep(1);
            }
            __syncthreads();
            __builtin_amdgcn_fence(__ATOMIC_ACQUIRE, "agent"); // inv L1/L2
        }

        // ---- stage th tile (16KB) with plain float4 loads ----
        {
            const f4* src = (const f4*)(cur + (size_t)pb * 4096);
            f4 v0 = src[tid], v1 = src[tid + 512];
            ((f4*)th_lds)[tid]       = v0;
            ((f4*)th_lds)[tid + 512] = v1;
        }
        __syncthreads();

        // ---- MAC: 512 fma vs pinned J ----
        float a00 = 0.f, a01 = 0.f, a02 = 0.f, a03 = 0.f;
        float a10 = 0.f, a11 = 0.f, a12 = 0.f, a13 = 0.f;
        float a20 = 0.f, a21 = 0.f, a22 = 0.f, a23 = 0.f;
        float a30 = 0.f, a31 = 0.f, a32 = 0.f, a33 = 0.f;
        STEPJ(0) STEPJ(1) STEPJ(2) STEPJ(3)
        STEPJ(4) STEPJ(5) STEPJ(6) STEPJ(7)

        // ---- K-reduction partials (ds_write_b128, conflict-profile as r3: 0) ----
        *(f4*)&red[ks * 272 +  0 + ng4 * 4] = (f4){a00, a01, a02, a03};
        *(f4*)&red[ks * 272 + 68 + ng4 * 4] = (f4){a10, a11, a12, a13};
        *(f4*)&red[ks * 272 + 136 + ng4 * 4] = (f4){a20, a21, a22, a23};
        *(f4*)&red[ks * 272 + 204 + ng4 * 4] = (f4){a30, a31, a32, a33};
        __syncthreads();

        // ---- owners: reduce 32 partials, h update, publish tanh(h) ----
        if (tid < 256) {
            float s = 0.f;
            #pragma unroll
            for (int k = 0; k < 32; ++k)
                s += red[k * 272 + bo * 68 + nl];
            float drive = s + nz + xa * is0 * w0 + xb * is1 * w1;
            hreg = 0.9f * hreg + 0.1f * drive;
            __hip_atomic_store(nxt + (size_t)bg * NE + ng_, fast_tanh(hreg),
                               __ATOMIC_RELAXED, __HIP_MEMORY_SCOPE_AGENT);
            if (bt == t + 1)
                __hip_atomic_store(last + (size_t)bg * NE + ng_, hreg,
                                   __ATOMIC_RELAXED, __HIP_MEMORY_SCOPE_AGENT);
        }
        __syncthreads();   // drains owners' stores (vmcnt) before arrive

        // ---- arrive ----
        if (tid == 0)
            __hip_atomic_fetch_add(cnt, 1u, __ATOMIC_RELEASE,
                                   __HIP_MEMORY_SCOPE_AGENT);
    }
}

// ---- tail ----
__global__ __launch_bounds__(256)
void wproj(const float* __restrict__ last_enc, const float* __restrict__ W,
           const float* __restrict__ bW, float* __restrict__ dec_traj)
{
    __shared__ float tl[NE];
    const int b = blockIdx.x;
    for (int k = threadIdx.x; k < NE; k += 256)
        tl[k] = tanhf(last_enc[(size_t)b * NE + k]);
    __syncthreads();
    const int wave = threadIdx.x >> 6;
    const int lane = threadIdx.x & 63;
    for (int m = wave; m < ND; m += 4) {
        const float4* Wr = (const float4*)(W + (size_t)m * NE);
        float acc = 0.f;
        #pragma unroll
        for (int it = 0; it < 4; ++it) {
            float4 wv = Wr[lane + it * 64];
            const float* tp = &tl[(lane + it * 64) * 4];
            acc = fmaf(wv.x, tp[0], acc);
            acc = fmaf(wv.y, tp[1], acc);
            acc = fmaf(wv.z, tp[2], acc);
            acc = fmaf(wv.w, tp[3], acc);
        }
        acc += __shfl_down(acc, 32); acc += __shfl_down(acc, 16);
        acc += __shfl_down(acc, 8);  acc += __shfl_down(acc, 4);
        acc += __shfl_down(acc, 2);  acc += __shfl_down(acc, 1);
        if (lane == 0) dec_traj[(size_t)b * 4 * ND + m] = acc + bW[m];
    }
}

__global__ __launch_bounds__(256)
void dec_step(const float* __restrict__ Q, float* __restrict__ dec_traj, int s)
{
    __shared__ float prev[ND];
    const int b = blockIdx.x;
    const float* pin = dec_traj + (size_t)b * 4 * ND + (size_t)(s - 1) * ND;
    for (int k = threadIdx.x; k < ND; k += 256) prev[k] = pin[k];
    __syncthreads();
    const int wave = threadIdx.x >> 6;
    const int lane = threadIdx.x & 63;
    for (int m = wave; m < ND; m += 4) {
        const float4* Qr = (const float4*)(Q + (size_t)m * ND);
        float acc = 0.f;
        #pragma unroll
        for (int it = 0; it < 2; ++it) {
            float4 qv = Qr[lane + it * 64];
            const float* tp = &prev[(lane + it * 64) * 4];
            acc = fmaf(qv.x, tp[0], acc);
            acc = fmaf(qv.y, tp[1], acc);
            acc = fmaf(qv.z, tp[2], acc);
            acc = fmaf(qv.w, tp[3], acc);
        }
        acc += __shfl_down(acc, 32); acc += __shfl_down(acc, 16);
        acc += __shfl_down(acc, 8);  acc += __shfl_down(acc, 4);
        acc += __shfl_down(acc, 2);  acc += __shfl_down(acc, 1);
        if (lane == 0)
            dec_traj[(size_t)b * 4 * ND + (size_t)s * ND + m] = acc;
    }
}

__global__ __launch_bounds__(256)
void out_proj(const float* __restrict__ dec_traj, const float* __restrict__ W_out,
              const float* __restrict__ out_s, float* __restrict__ Out)
{
    const int b = blockIdx.x;
    const int s = threadIdx.x >> 6;
    const int lane = threadIdx.x & 63;
    const float4* dp = (const float4*)(dec_traj + (size_t)b * 4 * ND + (size_t)s * ND);
    const float4* w0 = (const float4*)(W_out);
    const float4* w1 = (const float4*)(W_out + ND);
    float a0 = 0.f, a1 = 0.f;
    #pragma unroll
    for (int it = 0; it < 2; ++it) {
        float4 v  = dp[lane + it * 64];
        float4 u0 = w0[lane + it * 64];
        float4 u1 = w1[lane + it * 64];
        a0 = fmaf(v.x, u0.x, fmaf(v.y, u0.y, fmaf(v.z, u0.z, fmaf(v.w, u0.w, a0))));
        a1 = fmaf(v.x, u1.x, fmaf(v.y, u1.y, fmaf(v.z, u1.z, fmaf(v.w, u1.w, a1))));
    }
    for (int off = 32; off; off >>= 1) {
        a0 += __shfl_down(a0, off);
        a1 += __shfl_down(a1, off);
    }
    if (lane == 0) {
        Out[(size_t)b * 8 + s * 2 + 0] = out_s[0] * a0;
        Out[(size_t)b * 8 + s * 2 + 1] = out_s[1] * a1;
    }
}

extern "C" void kernel_launch(void* const* d_in, const int* in_sizes, int n_in,
                              void* d_out, int out_size, void* d_ws, size_t ws_size,
                              hipStream_t stream) {
    const float* X      = (const float*)d_in[0];
    const float* noise  = (const float*)d_in[1];
    const float* W_in   = (const float*)d_in[2];
    const float* J      = (const float*)d_in[3];
    const float* W      = (const float*)d_in[4];
    const float* bW     = (const float*)d_in[5];
    const float* Q      = (const float*)d_in[6];
    const float* W_out  = (const float*)d_in[7];
    const float* in_s   = (const float*)d_in[8];
    const float* out_s  = (const float*)d_in[9];
    const int*   BT     = (const int*)d_in[10];

    float* ws   = (float*)d_ws;
    float* th0  = ws + WS_TH0;
    float* th1  = ws + WS_TH1;
    float* last = ws + WS_LAST;
    unsigned* bar = (unsigned*)(ws + WS_BAR);

    float* out      = (float*)d_out;               // dec_traj (64,4,512)
    float* out_tail = out + (size_t)B_ * 4 * ND;   // Output (64,4,2)

    init_ws<<<193, 256, 0, stream>>>((float4*)ws);
    enc_persist<<<256, 512, 0, stream>>>(X, noise, W_in, J, in_s, BT,
                                         th0, th1, last, bar);
    wproj<<<B_, 256, 0, stream>>>(last, W, bW, out);
    for (int s = 1; s <= 3; ++s)
        dec_step<<<B_, 256, 0, stream>>>(Q, out, s);
    out_proj<<<B_, 256, 0, stream>>>(out, W_out, out_s, out_tail);
}

// Round 5
// 4165.864 us; speedup vs baseline: 1.9146x; 1.9146x over previous
//
#include <hip/hip_runtime.h>

#define B_   64
#define T_   512
#define NE   1024
#define ND   512

typedef float f4 __attribute__((ext_vector_type(4)));

// ---------------- ws layout (floats) ----------------
#define WS_TH0   0         // th buffer 0: [64][1024]
#define WS_TH1   65536     // th buffer 1
#define WS_LAST  131072    // last_enc [64][1024]
#define WS_BAR   196608    // 16 groups x 16 slots x 32 uints = 8192 uints
#define WS_ZERO_F4 51200   // (196608 + 8192) / 4

__global__ __launch_bounds__(256) void init_ws(float4* __restrict__ ws4) {
    int i = blockIdx.x * 256 + threadIdx.x;
    if (i < WS_ZERO_F4) ws4[i] = make_float4(0.f, 0.f, 0.f, 0.f);
}

// inline, call-free tanh: 1 - 2/(e^{2x}+1)
__device__ __forceinline__ float fast_tanh(float x) {
    float e = __expf(2.0f * x);
    return 1.0f - 2.0f / (e + 1.0f);
}

#define MACQ(A, Jv, T) \
    A = fmaf(Jv.x, T.x, A); A = fmaf(Jv.y, T.y, A); \
    A = fmaf(Jv.z, T.z, A); A = fmaf(Jv.w, T.w, A);

#define STEPJ(j) { \
    const f4 t0 = *(const f4*)&th_lds[       ks4 + (j)*128]; \
    const f4 t1 = *(const f4*)&th_lds[1024 + ks4 + (j)*128]; \
    const f4 t2 = *(const f4*)&th_lds[2048 + ks4 + (j)*128]; \
    const f4 t3 = *(const f4*)&th_lds[3072 + ks4 + (j)*128]; \
    MACQ(a00, J0_##j, t0) MACQ(a01, J1_##j, t0) MACQ(a02, J2_##j, t0) MACQ(a03, J3_##j, t0) \
    MACQ(a10, J0_##j, t1) MACQ(a11, J1_##j, t1) MACQ(a12, J2_##j, t1) MACQ(a13, J3_##j, t1) \
    MACQ(a20, J0_##j, t2) MACQ(a21, J1_##j, t2) MACQ(a22, J2_##j, t2) MACQ(a23, J3_##j, t2) \
    MACQ(a30, J0_##j, t3) MACQ(a31, J1_##j, t3) MACQ(a32, J2_##j, t3) MACQ(a33, J3_##j, t3) }

#define JLOAD(ni) \
    J##ni##_0 = *(const f4*)(Jp##ni +   0); J##ni##_1 = *(const f4*)(Jp##ni + 128); \
    J##ni##_2 = *(const f4*)(Jp##ni + 256); J##ni##_3 = *(const f4*)(Jp##ni + 384); \
    J##ni##_4 = *(const f4*)(Jp##ni + 512); J##ni##_5 = *(const f4*)(Jp##ni + 640); \
    J##ni##_6 = *(const f4*)(Jp##ni + 768); J##ni##_7 = *(const f4*)(Jp##ni + 896);

#define JPIN(ni) \
    asm volatile("" : "+v"(J##ni##_0)); asm volatile("" : "+v"(J##ni##_1)); \
    asm volatile("" : "+v"(J##ni##_2)); asm volatile("" : "+v"(J##ni##_3)); \
    asm volatile("" : "+v"(J##ni##_4)); asm volatile("" : "+v"(J##ni##_5)); \
    asm volatile("" : "+v"(J##ni##_6)); asm volatile("" : "+v"(J##ni##_7));

// Persistent encoder: 256 blocks (1/CU — forced by 112KB LDS), 512 threads.
// Block (pb=bid>>4, ng=bid&15): batches [pb*4,+4), neurons [ng*64,+64).
// Thread (ks=tid>>4, ng4=tid&15): 4n x 4b x 32k tile; J pinned in 32 f4 regs.
// The oversized `red` array is intentional: 112KB LDS -> 1 block/CU ->
// 2 waves/EU -> compiler VGPR budget 256 (vs 85 at 3 blocks/CU), which is
// what lets the 128-float J fragment stay register-resident.
__global__ __launch_bounds__(512, 2)
void enc_persist(const float* __restrict__ X, const float* __restrict__ noise,
                 const float* __restrict__ W_in, const float* __restrict__ J,
                 const float* __restrict__ in_s, const int* __restrict__ BT,
                 float* __restrict__ th0, float* __restrict__ th1,
                 float* __restrict__ last, unsigned* __restrict__ bar)
{
    __shared__ float th_lds[4096];    // 4 batches x 1024 (16 KB)
    __shared__ float red[24576];      // first 8704 used; rest = occupancy forcing (96 KB)

    const int tid = threadIdx.x;
    const int bid = blockIdx.x;
    const int pb  = bid >> 4;
    const int nb  = (bid & 15) * 64;
    const int ks  = tid >> 4;
    const int ng4 = tid & 15;
    const int ks4 = ks * 4;

    // ---- J fragment -> 32 named f4 (128 VGPRs) ----
    const float* Jp0 = J + (size_t)(nb + ng4 * 4 + 0) * NE + ks4;
    const float* Jp1 = J + (size_t)(nb + ng4 * 4 + 1) * NE + ks4;
    const float* Jp2 = J + (size_t)(nb + ng4 * 4 + 2) * NE + ks4;
    const float* Jp3 = J + (size_t)(nb + ng4 * 4 + 3) * NE + ks4;
    f4 J0_0, J0_1, J0_2, J0_3, J0_4, J0_5, J0_6, J0_7;
    f4 J1_0, J1_1, J1_2, J1_3, J1_4, J1_5, J1_6, J1_7;
    f4 J2_0, J2_1, J2_2, J2_3, J2_4, J2_5, J2_6, J2_7;
    f4 J3_0, J3_1, J3_2, J3_3, J3_4, J3_5, J3_6, J3_7;
    JLOAD(0) JLOAD(1) JLOAD(2) JLOAD(3)
    JPIN(0) JPIN(1) JPIN(2) JPIN(3)

    // ---- owner state ----
    const int bo  = tid >> 6;
    const int nl  = tid & 63;
    const int bg  = pb * 4 + bo;
    const int ng_ = nb + nl;
    float hreg = 0.f, w0 = 0.f, w1 = 0.f;
    int bt = -999;
    const float is0 = in_s[0], is1 = in_s[1];
    if (tid < 256) {
        w0 = W_in[ng_ * 2 + 0];
        w1 = W_in[ng_ * 2 + 1];
        bt = BT[bg];
    }

    const int m = max(max(BT[pb * 4 + 0], BT[pb * 4 + 1]),
                      max(BT[pb * 4 + 2], BT[pb * 4 + 3]));

    unsigned* slots  = bar + pb * 512;            // 16 slots, 128B apart
    unsigned* myslot = slots + (bid & 15) * 32;

    for (int t = 0; t < m; ++t) {
        float* __restrict__ cur = (t & 1) ? th1 : th0;
        float* __restrict__ nxt = (t & 1) ? th0 : th1;

        // ---- prefetch drive terms (immutable inputs, issued before gate) ----
        float nz = 0.f, xa = 0.f, xb = 0.f;
        if (tid < 256) {
            nz = noise[((size_t)bg * T_ + t) * NE + ng_];
            xa = X[((size_t)bg * T_ + t) * 2 + 0];
            xb = X[((size_t)bg * T_ + t) * 2 + 1];
        }

        // ---- gate: all 16 group blocks published step t-1? (wave-parallel poll) ----
        if (t > 0) {
            if (tid < 64) {
                unsigned* sp = slots + (tid & 15) * 32;
                for (;;) {
                    unsigned v = __hip_atomic_load(sp, __ATOMIC_RELAXED,
                                                   __HIP_MEMORY_SCOPE_AGENT);
                    if (__all(v >= (unsigned)t)) break;
                    __builtin_amdgcn_s_sleep(1);
                }
            }
            __syncthreads();
        }

        // ---- stage th tile (16KB) via LLC-coherent scalar loads ----
        {
            const float* src = cur + (size_t)pb * 4096;
            #pragma unroll
            for (int j = 0; j < 8; ++j)
                th_lds[tid + j * 512] =
                    __hip_atomic_load(src + tid + j * 512, __ATOMIC_RELAXED,
                                      __HIP_MEMORY_SCOPE_AGENT);
        }
        __syncthreads();

        // ---- re-pin J each iteration: spilling is now strictly unprofitable ----
        JPIN(0) JPIN(1) JPIN(2) JPIN(3)

        // ---- MAC: 512 fma vs register J ----
        float a00 = 0.f, a01 = 0.f, a02 = 0.f, a03 = 0.f;
        float a10 = 0.f, a11 = 0.f, a12 = 0.f, a13 = 0.f;
        float a20 = 0.f, a21 = 0.f, a22 = 0.f, a23 = 0.f;
        float a30 = 0.f, a31 = 0.f, a32 = 0.f, a33 = 0.f;
        STEPJ(0) STEPJ(1) STEPJ(2) STEPJ(3)
        STEPJ(4) STEPJ(5) STEPJ(6) STEPJ(7)

        // ---- K-reduction partials (ds_write_b128; 0 conflicts measured) ----
        *(f4*)&red[ks * 272 +   0 + ng4 * 4] = (f4){a00, a01, a02, a03};
        *(f4*)&red[ks * 272 +  68 + ng4 * 4] = (f4){a10, a11, a12, a13};
        *(f4*)&red[ks * 272 + 136 + ng4 * 4] = (f4){a20, a21, a22, a23};
        *(f4*)&red[ks * 272 + 204 + ng4 * 4] = (f4){a30, a31, a32, a33};
        __syncthreads();

        // ---- owners: reduce 32 partials, h update, publish tanh(h) ----
        if (tid < 256) {
            float s = 0.f;
            #pragma unroll
            for (int k = 0; k < 32; ++k)
                s += red[k * 272 + bo * 68 + nl];
            float drive = s + nz + xa * is0 * w0 + xb * is1 * w1;
            hreg = 0.9f * hreg + 0.1f * drive;
            __hip_atomic_store(nxt + (size_t)bg * NE + ng_, fast_tanh(hreg),
                               __ATOMIC_RELAXED, __HIP_MEMORY_SCOPE_AGENT);
            if (bt == t + 1)
                __hip_atomic_store(last + (size_t)bg * NE + ng_, hreg,
                                   __ATOMIC_RELAXED, __HIP_MEMORY_SCOPE_AGENT);
        }
        __syncthreads();   // drains vmcnt: publishes at LLC before arrive

        // ---- arrive: own slot, no RMW contention ----
        if (tid == 0)
            __hip_atomic_store(myslot, (unsigned)(t + 1),
                               __ATOMIC_RELEASE, __HIP_MEMORY_SCOPE_AGENT);
    }
}

// ---- tail ----
__global__ __launch_bounds__(256)
void wproj(const float* __restrict__ last_enc, const float* __restrict__ W,
           const float* __restrict__ bW, float* __restrict__ dec_traj)
{
    __shared__ float tl[NE];
    const int b = blockIdx.x;
    for (int k = threadIdx.x; k < NE; k += 256)
        tl[k] = tanhf(last_enc[(size_t)b * NE + k]);
    __syncthreads();
    const int wave = threadIdx.x >> 6;
    const int lane = threadIdx.x & 63;
    for (int m = wave; m < ND; m += 4) {
        const float4* Wr = (const float4*)(W + (size_t)m * NE);
        float acc = 0.f;
        #pragma unroll
        for (int it = 0; it < 4; ++it) {
            float4 wv = Wr[lane + it * 64];
            const float* tp = &tl[(lane + it * 64) * 4];
            acc = fmaf(wv.x, tp[0], acc);
            acc = fmaf(wv.y, tp[1], acc);
            acc = fmaf(wv.z, tp[2], acc);
            acc = fmaf(wv.w, tp[3], acc);
        }
        acc += __shfl_down(acc, 32); acc += __shfl_down(acc, 16);
        acc += __shfl_down(acc, 8);  acc += __shfl_down(acc, 4);
        acc += __shfl_down(acc, 2);  acc += __shfl_down(acc, 1);
        if (lane == 0) dec_traj[(size_t)b * 4 * ND + m] = acc + bW[m];
    }
}

__global__ __launch_bounds__(256)
void dec_step(const float* __restrict__ Q, float* __restrict__ dec_traj, int s)
{
    __shared__ float prev[ND];
    const int b = blockIdx.x;
    const float* pin = dec_traj + (size_t)b * 4 * ND + (size_t)(s - 1) * ND;
    for (int k = threadIdx.x; k < ND; k += 256) prev[k] = pin[k];
    __syncthreads();
    const int wave = threadIdx.x >> 6;
    const int lane = threadIdx.x & 63;
    for (int m = wave; m < ND; m += 4) {
        const float4* Qr = (const float4*)(Q + (size_t)m * ND);
        float acc = 0.f;
        #pragma unroll
        for (int it = 0; it < 2; ++it) {
            float4 qv = Qr[lane + it * 64];
            const float* tp = &prev[(lane + it * 64) * 4];
            acc = fmaf(qv.x, tp[0], acc);
            acc = fmaf(qv.y, tp[1], acc);
            acc = fmaf(qv.z, tp[2], acc);
            acc = fmaf(qv.w, tp[3], acc);
        }
        acc += __shfl_down(acc, 32); acc += __shfl_down(acc, 16);
        acc += __shfl_down(acc, 8);  acc += __shfl_down(acc, 4);
        acc += __shfl_down(acc, 2);  acc += __shfl_down(acc, 1);
        if (lane == 0)
            dec_traj[(size_t)b * 4 * ND + (size_t)s * ND + m] = acc;
    }
}

__global__ __launch_bounds__(256)
void out_proj(const float* __restrict__ dec_traj, const float* __restrict__ W_out,
              const float* __restrict__ out_s, float* __restrict__ Out)
{
    const int b = blockIdx.x;
    const int s = threadIdx.x >> 6;
    const int lane = threadIdx.x & 63;
    const float4* dp = (const float4*)(dec_traj + (size_t)b * 4 * ND + (size_t)s * ND);
    const float4* w0 = (const float4*)(W_out);
    const float4* w1 = (const float4*)(W_out + ND);
    float a0 = 0.f, a1 = 0.f;
    #pragma unroll
    for (int it = 0; it < 2; ++it) {
        float4 v  = dp[lane + it * 64];
        float4 u0 = w0[lane + it * 64];
        float4 u1 = w1[lane + it * 64];
        a0 = fmaf(v.x, u0.x, fmaf(v.y, u0.y, fmaf(v.z, u0.z, fmaf(v.w, u0.w, a0))));
        a1 = fmaf(v.x, u1.x, fmaf(v.y, u1.y, fmaf(v.z, u1.z, fmaf(v.w, u1.w, a1))));
    }
    for (int off = 32; off; off >>= 1) {
        a0 += __shfl_down(a0, off);
        a1 += __shfl_down(a1, off);
    }
    if (lane == 0) {
        Out[(size_t)b * 8 + s * 2 + 0] = out_s[0] * a0;
        Out[(size_t)b * 8 + s * 2 + 1] = out_s[1] * a1;
    }
}

extern "C" void kernel_launch(void* const* d_in, const int* in_sizes, int n_in,
                              void* d_out, int out_size, void* d_ws, size_t ws_size,
                              hipStream_t stream) {
    const float* X      = (const float*)d_in[0];
    const float* noise  = (const float*)d_in[1];
    const float* W_in   = (const float*)d_in[2];
    const float* J      = (const float*)d_in[3];
    const float* W      = (const float*)d_in[4];
    const float* bW     = (const float*)d_in[5];
    const float* Q      = (const float*)d_in[6];
    const float* W_out  = (const float*)d_in[7];
    const float* in_s   = (const float*)d_in[8];
    const float* out_s  = (const float*)d_in[9];
    const int*   BT     = (const int*)d_in[10];

    float* ws   = (float*)d_ws;
    float* th0  = ws + WS_TH0;
    float* th1  = ws + WS_TH1;
    float* last = ws + WS_LAST;
    unsigned* bar = (unsigned*)(ws + WS_BAR);

    float* out      = (float*)d_out;               // dec_traj (64,4,512)
    float* out_tail = out + (size_t)B_ * 4 * ND;   // Output (64,4,2)

    init_ws<<<200, 256, 0, stream>>>((float4*)ws);
    enc_persist<<<256, 512, 0, stream>>>(X, noise, W_in, J, in_s, BT,
                                         th0, th1, last, bar);
    wproj<<<B_, 256, 0, stream>>>(last, W, bW, out);
    for (int s = 1; s <= 3; ++s)
        dec_step<<<B_, 256, 0, stream>>>(Q, out, s);
    out_proj<<<B_, 256, 0, stream>>>(out, W_out, out_s, out_tail);
}